// Round 15
// baseline (127.532 us; speedup 1.0000x reference)
//
#include <hip/hip_runtime.h>
#include <hip/hip_bf16.h>
#include <math.h>

#define NN    8
#define HH    64
#define WW    64
#define HW    4096
#define NHW   32768
#define DALL  384     // 256 value + 112 om + 16 pad
#define EPSBN 1e-5f

typedef __attribute__((ext_vector_type(8))) short short8v;
typedef __attribute__((ext_vector_type(4))) float f32x4;
typedef __attribute__((ext_vector_type(2))) float f32x2;

__device__ __forceinline__ float b2f(unsigned short u) {
    union { unsigned int i; float f; } v; v.i = ((unsigned int)u) << 16; return v.f;
}
__device__ __forceinline__ unsigned short f2b(float f) {
    __hip_bfloat16 h = __float2bfloat16(f);
    return *reinterpret_cast<const unsigned short*>(&h);
}
// dword of 2 bf16 -> f32x2 (lo, hi)
__device__ __forceinline__ f32x2 bf2x(int u) {
    union { int i; float f; } a, b;
    a.i = u << 16;
    b.i = u & 0xffff0000;
    f32x2 r; r[0] = a.f; r[1] = b.f; return r;
}

// Workspace layout (bytes):
//  VO     [NHW][384] bf16  @ 0          (25165824)
//  Wallbf [384][256] bf16  @ 25165824   (196608)
//  Woutbf [256][256] bf16  @ 25362432   (131072)
//  ball   [384] f32        @ 25493504   (1536)
//  bout   [256] f32        @ 25495040   (1024)

// ---------------- prep: fold weights (f32 math, 4-way ILP) ----------------
__global__ __launch_bounds__(256)
void prep_kernel(const float* __restrict__ cv1_w, const float* __restrict__ cv1_b,
                 const float* __restrict__ value_w, const float* __restrict__ value_b,
                 const float* __restrict__ dw_w, const float* __restrict__ dw_b,
                 const float* __restrict__ om_w, const float* __restrict__ om_b,
                 const float* __restrict__ out_w, const float* __restrict__ cv2_w,
                 const float* __restrict__ bn_g, const float* __restrict__ bn_b,
                 const float* __restrict__ bn_m, const float* __restrict__ bn_v,
                 unsigned short* __restrict__ Wallbf, float* __restrict__ ball,
                 unsigned short* __restrict__ Woutbf, float* __restrict__ bout)
{
    int job = blockIdx.x * 256 + threadIdx.x;
    if (job < 65536) {                          // Wv = value_w @ cv1_w
        int d = job >> 8, cc = job & 255;
        float s0=0.f, s1=0.f, s2=0.f, s3=0.f;
        for (int e = 0; e < 256; e += 4) {
            float4 wv = *reinterpret_cast<const float4*>(&value_w[d*256+e]);
            s0 = fmaf(wv.x, cv1_w[(e+0)*256+cc], s0);
            s1 = fmaf(wv.y, cv1_w[(e+1)*256+cc], s1);
            s2 = fmaf(wv.z, cv1_w[(e+2)*256+cc], s2);
            s3 = fmaf(wv.w, cv1_w[(e+3)*256+cc], s3);
        }
        Wallbf[job] = f2b((s0+s1)+(s2+s3));
    } else if (job < 94208) {                   // Wom = om_w.diag(dw_w) @ cv1_w
        int idx = job - 65536;
        int o = idx >> 8, cc = idx & 255;
        float s0=0.f, s1=0.f, s2=0.f, s3=0.f;
        for (int e = 0; e < 256; e += 4) {
            float4 wv = *reinterpret_cast<const float4*>(&om_w[o*256+e]);
            float4 dv = *reinterpret_cast<const float4*>(&dw_w[e]);
            s0 = fmaf(wv.x*dv.x, cv1_w[(e+0)*256+cc], s0);
            s1 = fmaf(wv.y*dv.y, cv1_w[(e+1)*256+cc], s1);
            s2 = fmaf(wv.z*dv.z, cv1_w[(e+2)*256+cc], s2);
            s3 = fmaf(wv.w*dv.w, cv1_w[(e+3)*256+cc], s3);
        }
        Wallbf[job] = f2b((s0+s1)+(s2+s3));
    } else if (job < 98304) {                   // pad rows 368..383
        Wallbf[job] = 0;
    } else if (job < 163840) {                  // Wout = diag(s) cv2_w @ out_w
        int idx = job - 98304;
        int d = idx >> 8, cc = idx & 255;
        float s0=0.f, s1=0.f, s2=0.f, s3=0.f;
        for (int e = 0; e < 256; e += 4) {
            float4 wv = *reinterpret_cast<const float4*>(&cv2_w[d*256+e]);
            s0 = fmaf(wv.x, out_w[(e+0)*256+cc], s0);
            s1 = fmaf(wv.y, out_w[(e+1)*256+cc], s1);
            s2 = fmaf(wv.z, out_w[(e+2)*256+cc], s2);
            s3 = fmaf(wv.w, out_w[(e+3)*256+cc], s3);
        }
        float sc = bn_g[d] * rsqrtf(bn_v[d] + EPSBN);
        Woutbf[idx] = f2b(((s0+s1)+(s2+s3)) * sc);
    } else if (job < 164096) {                  // bv
        int d = job - 163840;
        float s = value_b[d];
        for (int e = 0; e < 256; ++e) s = fmaf(value_w[d*256+e], cv1_b[e], s);
        ball[d] = s;
    } else if (job < 164208) {                  // bom
        int o = job - 164096;
        float s = om_b[o];
        for (int e = 0; e < 256; ++e)
            s = fmaf(om_w[o*256+e], fmaf(dw_w[e], cv1_b[e], dw_b[e]), s);
        ball[256 + o] = s;
    } else if (job < 164224) {                  // ball pad
        ball[368 + job - 164208] = 0.f;
    } else if (job < 164480) {                  // bout
        int d = job - 164224;
        float sc = bn_g[d] * rsqrtf(bn_v[d] + EPSBN);
        bout[d] = fmaf(-bn_m[d], sc, bn_b[d]);
    }
}

// ---------------- GEMM1 (fused x-transpose): VO = bf16(x)^T @ Wallbf^T + ball ----------------
__global__ __launch_bounds__(256)
void gemm_vo_kernel(const float* __restrict__ x, const unsigned short* __restrict__ Wallbf,
                    const float* __restrict__ ball, unsigned short* __restrict__ VO)
{
    __shared__ unsigned short As[8192];
    __shared__ unsigned short Bs[8192];
    int t = threadIdx.x;
    int m0 = blockIdx.y * 128;   // pixel tile
    int n0 = blockIdx.x * 128;   // output-channel tile
    int nimg = m0 >> 12, hw0 = m0 & 4095;
    int lane = t & 63;
    int wv = t >> 6;
    int wr = wv >> 1, wc = wv & 1;
    int r_l = lane & 15, kg_l = lane >> 4;
    int ci = t >> 6;             // c-chunk (16 ch) for A staging
    int l  = t & 63;             // row-pair for A staging

    const float* xbase = x + (size_t)(nimg * 256) * 4096 + hw0;

    f32x4 acc[4][4] = {};

    for (int kt = 0; kt < 4; ++kt) {
        int c0 = kt * 64;
        float2 val[16];
        #pragma unroll
        for (int i = 0; i < 16; ++i)
            val[i] = *reinterpret_cast<const float2*>(
                &xbase[(size_t)(c0 + ci*16 + i) * 4096 + 2*l]);
        __syncthreads();   // prior MFMA reads done before overwrite
        #pragma unroll
        for (int rsel = 0; rsel < 2; ++rsel) {
            int row = 2*l + rsel;
            #pragma unroll
            for (int kgi = 0; kgi < 2; ++kgi) {
                int kg = ci*2 + kgi;
                short8v s;
                #pragma unroll
                for (int j = 0; j < 8; ++j)
                    s[j] = (short)f2b(rsel ? val[kgi*8+j].y : val[kgi*8+j].x);
                *reinterpret_cast<short8v*>(&As[row*64 + ((kg ^ (row & 7)) << 3)]) = s;
            }
        }
        #pragma unroll
        for (int i = 0; i < 4; ++i) {
            int idx = t + i*256;
            int row = idx >> 3, kg = idx & 7;
            *reinterpret_cast<short8v*>(&Bs[row*64 + ((kg ^ (row & 7)) << 3)]) =
                *reinterpret_cast<const short8v*>(&Wallbf[(size_t)(n0 + row)*256 + c0 + kg*8]);
        }
        __syncthreads();
        #pragma unroll
        for (int ks = 0; ks < 2; ++ks) {
            short8v af[4], bfr[4];
            #pragma unroll
            for (int m = 0; m < 4; ++m) {
                int row = wr*64 + m*16 + r_l;
                af[m] = *reinterpret_cast<const short8v*>(
                    &As[row*64 + (((ks*4 + kg_l) ^ (row & 7)) << 3)]);
            }
            #pragma unroll
            for (int n = 0; n < 4; ++n) {
                int row = wc*64 + n*16 + r_l;
                bfr[n] = *reinterpret_cast<const short8v*>(
                    &Bs[row*64 + (((ks*4 + kg_l) ^ (row & 7)) << 3)]);
            }
            #pragma unroll
            for (int m = 0; m < 4; ++m)
                #pragma unroll
                for (int n = 0; n < 4; ++n)
                    acc[m][n] = __builtin_amdgcn_mfma_f32_16x16x32_bf16(af[m], bfr[n], acc[m][n], 0, 0, 0);
        }
    }

    #pragma unroll
    for (int n = 0; n < 4; ++n) {
        int d = n0 + wc*64 + n*16 + r_l;
        float bb = ball[d];
        #pragma unroll
        for (int m = 0; m < 4; ++m) {
            int pr = m0 + wr*64 + m*16 + (kg_l << 2);
            #pragma unroll
            for (int r = 0; r < 4; ++r)
                VO[(size_t)(pr + r)*384 + d] = f2b(acc[m][n][r] + bb);
        }
    }
}

// ---------------- fused DCNv4 + GEMM2: out = SiLU(Wout @ dcn(VO)^T + bout) ----------------
// Block = 32 px (half an image row) x 512 threads, grid 1024.
// Phase 1: dcn (round-6 inner loop, direct global gathers) -> y tile (32px x 256ch)
//          in LDS, written in GEMM-B swizzled layout (4 sections [g][32px][64k]).
// Phase 2: 8-wave MFMA (M=256 d, N=32 px, K=256); A = Woutbf staged per K-tile
//          into u_buf (union-shared with phase-1 om_s f32).
// LDS 48 KB -> 3 blocks/CU; grid 1024 -> 4/CU; net 24 waves/CU (vs round-13's 16).
__global__ __launch_bounds__(512, 6)
void dcn_gemm_kernel(const unsigned short* __restrict__ VO,
                     const unsigned short* __restrict__ Woutbf,
                     const float* __restrict__ bout, float* __restrict__ out)
{
    __shared__ unsigned short y_lds[8192];    // 16 KB: 4 sections x [32px][64k], swizzled
    __shared__ char u_buf[32768];             // 32 KB: phase1 om_s f32[32][108] | phase2 As
    float* om_s = reinterpret_cast<float*>(u_buf);
    unsigned short* As = reinterpret_cast<unsigned short*>(u_buf);

    int t = threadIdx.x;
    int bid = blockIdx.x;                     // 1024 blocks = 8 XCD x 128
    int logical = ((bid & 7) << 7) + (bid >> 3);   // image == XCD
    int nimg = logical >> 7;
    int hw0 = (logical & 127) * 32;           // half-row start
    int h = hw0 >> 6;
    int w0 = hw0 & 63;                        // 0 or 32

    const unsigned short* vimg = VO + (size_t)nimg * (HW * (size_t)DALL);

    // ---- stage om (f32) for 32 px ----
    for (int i = t; i < 3456; i += 512) {
        int pl = i / 108, j = i - pl * 108;
        om_s[pl * 108 + j] = b2f(vimg[(size_t)(hw0 + pl) * DALL + 256 + j]);
    }
    __syncthreads();

    // ---- phase 1: dcn, 2 slots per thread ----
    int ch8 = t & 7;
    #pragma unroll
    for (int iter = 0; iter < 2; ++iter) {
        int slotIdx = iter * 64 + (t >> 3);   // 0..127
        int px = slotIdx >> 2, g = slotIdx & 3;
        int w = w0 + px;
        const unsigned short* vbase = vimg + g*64 + ch8*8;
        const float* o = om_s + px*108 + g*27;

        f32x2 acc2[4] = {};
        #pragma unroll
        for (int k = 0; k < 9; ++k) {
            float dxo = o[2*k], dyo = o[2*k+1], m = o[18+k];
            float pxf = (float)(w + (k % 3) - 1) + dxo;
            float pyf = (float)(h + (k / 3) - 1) + dyo;
            float x0f = floorf(pxf), y0f = floorf(pyf);
            float fx = pxf - x0f, fy = pyf - y0f;
            int x0 = (int)x0f, y0 = (int)y0f;
            #pragma unroll
            for (int dyy = 0; dyy < 2; ++dyy) {
                #pragma unroll
                for (int dxx = 0; dxx < 2; ++dxx) {
                    int yy = y0 + dyy, xx = x0 + dxx;
                    bool valid = (yy >= 0) & (yy < HH) & (xx >= 0) & (xx < WW);
                    float wgt = (dyy ? fy : 1.f - fy) * (dxx ? fx : 1.f - fx);
                    float wmc = valid ? (m * wgt) : 0.f;
                    int yc = min(max(yy, 0), HH - 1);
                    int xc = min(max(xx, 0), WW - 1);
                    int4 v = *reinterpret_cast<const int4*>(
                        &vbase[((yc << 6) + xc) * DALL]);
                    f32x2 wm2; wm2[0] = wmc; wm2[1] = wmc;
                    int vv[4] = {v.x, v.y, v.z, v.w};
                    #pragma unroll
                    for (int q = 0; q < 4; ++q)
                        acc2[q] += bf2x(vv[q]) * wm2;
                }
            }
        }
        short8v ov;
        #pragma unroll
        for (int q = 0; q < 4; ++q) {
            ov[2*q]   = (short)f2b(acc2[q][0]);
            ov[2*q+1] = (short)f2b(acc2[q][1]);
        }
        // write into section g, row px, kg = ch8 (B-swizzled)
        *reinterpret_cast<short8v*>(
            &y_lds[g*2048 + px*64 + ((ch8 ^ (px & 7)) << 3)]) = ov;
    }

    // ---- phase 2: GEMM (M=256 d, N=32 px, K=256), A staged per K-tile ----
    int lane = t & 63;
    int wv = t >> 6;                          // 8 waves
    int wr = wv >> 1, wc = wv & 1;            // wr: 64-d band, wc: 16-px band
    int r_l = lane & 15, kg_l = lane >> 4;

    f32x4 acc[4][1] = {};
    for (int kt = 0; kt < 4; ++kt) {
        int c0 = kt * 64;
        __syncthreads();   // om_s/As free (phase1 done or prior kt MFMA done)
        #pragma unroll
        for (int i = 0; i < 4; ++i) {
            int idx = t + i * 512;            // 2048 jobs: row 0..255, kg 0..7
            int row = idx >> 3, kg = idx & 7;
            *reinterpret_cast<short8v*>(&As[row*64 + ((kg ^ (row & 7)) << 3)]) =
                *reinterpret_cast<const short8v*>(&Woutbf[(size_t)row*256 + c0 + kg*8]);
        }
        __syncthreads();
        #pragma unroll
        for (int ks = 0; ks < 2; ++ks) {
            short8v af[4], bfr;
            #pragma unroll
            for (int m = 0; m < 4; ++m) {
                int row = wr*64 + m*16 + r_l;
                af[m] = *reinterpret_cast<const short8v*>(
                    &As[row*64 + (((ks*4 + kg_l) ^ (row & 7)) << 3)]);
            }
            {
                int row = wc*16 + r_l;
                bfr = *reinterpret_cast<const short8v*>(
                    &y_lds[kt*2048 + row*64 + (((ks*4 + kg_l) ^ (row & 7)) << 3)]);
            }
            #pragma unroll
            for (int m = 0; m < 4; ++m)
                acc[m][0] = __builtin_amdgcn_mfma_f32_16x16x32_bf16(af[m], bfr, acc[m][0], 0, 0, 0);
        }
    }

    // ---- epilogue: bias + SiLU + NCHW f32 store ----
    #pragma unroll
    for (int m = 0; m < 4; ++m) {
        int dbase = wr*64 + m*16 + (kg_l << 2);
        #pragma unroll
        for (int r = 0; r < 4; ++r) {
            int d = dbase + r;
            float bb = bout[d];
            int pcol = wc*16 + r_l;
            float z = acc[m][0][r] + bb;
            float sv = z / (1.f + __expf(-z));
            out[((size_t)(nimg*256 + d))*4096 + hw0 + pcol] = sv;
        }
    }
}

extern "C" void kernel_launch(void* const* d_in, const int* in_sizes, int n_in,
                              void* d_out, int out_size, void* d_ws, size_t ws_size,
                              hipStream_t stream) {
    const float* x       = (const float*)d_in[0];
    const float* cv1_w   = (const float*)d_in[1];
    const float* cv1_b   = (const float*)d_in[2];
    const float* value_w = (const float*)d_in[3];
    const float* value_b = (const float*)d_in[4];
    const float* dw_w    = (const float*)d_in[5];
    const float* dw_b    = (const float*)d_in[6];
    const float* om_w    = (const float*)d_in[7];
    const float* om_b    = (const float*)d_in[8];
    const float* out_w   = (const float*)d_in[9];
    const float* cv2_w   = (const float*)d_in[10];
    const float* bn_g    = (const float*)d_in[11];
    const float* bn_b    = (const float*)d_in[12];
    const float* bn_m    = (const float*)d_in[13];
    const float* bn_v    = (const float*)d_in[14];

    char* ws = (char*)d_ws;
    unsigned short* VO     = (unsigned short*)(ws);
    unsigned short* Wallbf = (unsigned short*)(ws + 25165824);
    unsigned short* Woutbf = (unsigned short*)(ws + 25362432);
    float*          ball   = (float*)(ws + 25493504);
    float*          bout   = (float*)(ws + 25495040);
    float* out = (float*)d_out;

    prep_kernel<<<643, 256, 0, stream>>>(cv1_w, cv1_b, value_w, value_b, dw_w, dw_b,
                                         om_w, om_b, out_w, cv2_w,
                                         bn_g, bn_b, bn_m, bn_v,
                                         Wallbf, ball, Woutbf, bout);
    gemm_vo_kernel<<<dim3(3, 256), 256, 0, stream>>>(x, Wallbf, ball, VO);
    dcn_gemm_kernel<<<1024, 512, 0, stream>>>(VO, Woutbf, bout, out);
}

// Round 16
// 89.159 us; speedup vs baseline: 1.4304x; 1.4304x over previous
//
#include <hip/hip_runtime.h>
#include <hip/hip_bf16.h>
#include <math.h>

#define NN    8
#define HH    64
#define WW    64
#define HW    4096
#define NHW   32768
#define DALL  384     // 256 value + 112 om + 16 pad
#define EPSBN 1e-5f

typedef __attribute__((ext_vector_type(8))) short short8v;
typedef __attribute__((ext_vector_type(4))) float f32x4;
typedef __attribute__((ext_vector_type(2))) float f32x2;

__device__ __forceinline__ float b2f(unsigned short u) {
    union { unsigned int i; float f; } v; v.i = ((unsigned int)u) << 16; return v.f;
}
__device__ __forceinline__ unsigned short f2b(float f) {
    __hip_bfloat16 h = __float2bfloat16(f);
    return *reinterpret_cast<const unsigned short*>(&h);
}
// dword of 2 bf16 -> f32x2 (lo, hi)
__device__ __forceinline__ f32x2 bf2x(int u) {
    union { int i; float f; } a, b;
    a.i = u << 16;
    b.i = u & 0xffff0000;
    f32x2 r; r[0] = a.f; r[1] = b.f; return r;
}

// Workspace layout (bytes):
//  VO     [NHW][384] bf16  @ 0          (25165824)
//  Wallbf [384][256] bf16  @ 25165824   (196608)
//  Woutbf [256][256] bf16  @ 25362432   (131072)
//  ball   [384] f32        @ 25493504   (1536)
//  bout   [256] f32        @ 25495040   (1024)

// ---------------- prep: fold weights (f32 math, 4-way ILP) ----------------
__global__ __launch_bounds__(256)
void prep_kernel(const float* __restrict__ cv1_w, const float* __restrict__ cv1_b,
                 const float* __restrict__ value_w, const float* __restrict__ value_b,
                 const float* __restrict__ dw_w, const float* __restrict__ dw_b,
                 const float* __restrict__ om_w, const float* __restrict__ om_b,
                 const float* __restrict__ out_w, const float* __restrict__ cv2_w,
                 const float* __restrict__ bn_g, const float* __restrict__ bn_b,
                 const float* __restrict__ bn_m, const float* __restrict__ bn_v,
                 unsigned short* __restrict__ Wallbf, float* __restrict__ ball,
                 unsigned short* __restrict__ Woutbf, float* __restrict__ bout)
{
    int job = blockIdx.x * 256 + threadIdx.x;
    if (job < 65536) {                          // Wv = value_w @ cv1_w
        int d = job >> 8, cc = job & 255;
        float s0=0.f, s1=0.f, s2=0.f, s3=0.f;
        for (int e = 0; e < 256; e += 4) {
            float4 wv = *reinterpret_cast<const float4*>(&value_w[d*256+e]);
            s0 = fmaf(wv.x, cv1_w[(e+0)*256+cc], s0);
            s1 = fmaf(wv.y, cv1_w[(e+1)*256+cc], s1);
            s2 = fmaf(wv.z, cv1_w[(e+2)*256+cc], s2);
            s3 = fmaf(wv.w, cv1_w[(e+3)*256+cc], s3);
        }
        Wallbf[job] = f2b((s0+s1)+(s2+s3));
    } else if (job < 94208) {                   // Wom = om_w.diag(dw_w) @ cv1_w
        int idx = job - 65536;
        int o = idx >> 8, cc = idx & 255;
        float s0=0.f, s1=0.f, s2=0.f, s3=0.f;
        for (int e = 0; e < 256; e += 4) {
            float4 wv = *reinterpret_cast<const float4*>(&om_w[o*256+e]);
            float4 dv = *reinterpret_cast<const float4*>(&dw_w[e]);
            s0 = fmaf(wv.x*dv.x, cv1_w[(e+0)*256+cc], s0);
            s1 = fmaf(wv.y*dv.y, cv1_w[(e+1)*256+cc], s1);
            s2 = fmaf(wv.z*dv.z, cv1_w[(e+2)*256+cc], s2);
            s3 = fmaf(wv.w*dv.w, cv1_w[(e+3)*256+cc], s3);
        }
        Wallbf[job] = f2b((s0+s1)+(s2+s3));
    } else if (job < 98304) {                   // pad rows 368..383
        Wallbf[job] = 0;
    } else if (job < 163840) {                  // Wout = diag(s) cv2_w @ out_w
        int idx = job - 98304;
        int d = idx >> 8, cc = idx & 255;
        float s0=0.f, s1=0.f, s2=0.f, s3=0.f;
        for (int e = 0; e < 256; e += 4) {
            float4 wv = *reinterpret_cast<const float4*>(&cv2_w[d*256+e]);
            s0 = fmaf(wv.x, out_w[(e+0)*256+cc], s0);
            s1 = fmaf(wv.y, out_w[(e+1)*256+cc], s1);
            s2 = fmaf(wv.z, out_w[(e+2)*256+cc], s2);
            s3 = fmaf(wv.w, out_w[(e+3)*256+cc], s3);
        }
        float sc = bn_g[d] * rsqrtf(bn_v[d] + EPSBN);
        Woutbf[idx] = f2b(((s0+s1)+(s2+s3)) * sc);
    } else if (job < 164096) {                  // bv
        int d = job - 163840;
        float s = value_b[d];
        for (int e = 0; e < 256; ++e) s = fmaf(value_w[d*256+e], cv1_b[e], s);
        ball[d] = s;
    } else if (job < 164208) {                  // bom
        int o = job - 164096;
        float s = om_b[o];
        for (int e = 0; e < 256; ++e)
            s = fmaf(om_w[o*256+e], fmaf(dw_w[e], cv1_b[e], dw_b[e]), s);
        ball[256 + o] = s;
    } else if (job < 164224) {                  // ball pad
        ball[368 + job - 164208] = 0.f;
    } else if (job < 164480) {                  // bout
        int d = job - 164224;
        float sc = bn_g[d] * rsqrtf(bn_v[d] + EPSBN);
        bout[d] = fmaf(-bn_m[d], sc, bn_b[d]);
    }
}

// ---------------- GEMM1 (fused x-transpose): VO = bf16(x)^T @ Wallbf^T + ball ----------------
__global__ __launch_bounds__(256)
void gemm_vo_kernel(const float* __restrict__ x, const unsigned short* __restrict__ Wallbf,
                    const float* __restrict__ ball, unsigned short* __restrict__ VO)
{
    __shared__ unsigned short As[8192];
    __shared__ unsigned short Bs[8192];
    int t = threadIdx.x;
    int m0 = blockIdx.y * 128;   // pixel tile
    int n0 = blockIdx.x * 128;   // output-channel tile
    int nimg = m0 >> 12, hw0 = m0 & 4095;
    int lane = t & 63;
    int wv = t >> 6;
    int wr = wv >> 1, wc = wv & 1;
    int r_l = lane & 15, kg_l = lane >> 4;
    int ci = t >> 6;             // c-chunk (16 ch) for A staging
    int l  = t & 63;             // row-pair for A staging

    const float* xbase = x + (size_t)(nimg * 256) * 4096 + hw0;

    f32x4 acc[4][4] = {};

    for (int kt = 0; kt < 4; ++kt) {
        int c0 = kt * 64;
        float2 val[16];
        #pragma unroll
        for (int i = 0; i < 16; ++i)
            val[i] = *reinterpret_cast<const float2*>(
                &xbase[(size_t)(c0 + ci*16 + i) * 4096 + 2*l]);
        __syncthreads();   // prior MFMA reads done before overwrite
        #pragma unroll
        for (int rsel = 0; rsel < 2; ++rsel) {
            int row = 2*l + rsel;
            #pragma unroll
            for (int kgi = 0; kgi < 2; ++kgi) {
                int kg = ci*2 + kgi;
                short8v s;
                #pragma unroll
                for (int j = 0; j < 8; ++j)
                    s[j] = (short)f2b(rsel ? val[kgi*8+j].y : val[kgi*8+j].x);
                *reinterpret_cast<short8v*>(&As[row*64 + ((kg ^ (row & 7)) << 3)]) = s;
            }
        }
        #pragma unroll
        for (int i = 0; i < 4; ++i) {
            int idx = t + i*256;
            int row = idx >> 3, kg = idx & 7;
            *reinterpret_cast<short8v*>(&Bs[row*64 + ((kg ^ (row & 7)) << 3)]) =
                *reinterpret_cast<const short8v*>(&Wallbf[(size_t)(n0 + row)*256 + c0 + kg*8]);
        }
        __syncthreads();
        #pragma unroll
        for (int ks = 0; ks < 2; ++ks) {
            short8v af[4], bfr[4];
            #pragma unroll
            for (int m = 0; m < 4; ++m) {
                int row = wr*64 + m*16 + r_l;
                af[m] = *reinterpret_cast<const short8v*>(
                    &As[row*64 + (((ks*4 + kg_l) ^ (row & 7)) << 3)]);
            }
            #pragma unroll
            for (int n = 0; n < 4; ++n) {
                int row = wc*64 + n*16 + r_l;
                bfr[n] = *reinterpret_cast<const short8v*>(
                    &Bs[row*64 + (((ks*4 + kg_l) ^ (row & 7)) << 3)]);
            }
            #pragma unroll
            for (int m = 0; m < 4; ++m)
                #pragma unroll
                for (int n = 0; n < 4; ++n)
                    acc[m][n] = __builtin_amdgcn_mfma_f32_16x16x32_bf16(af[m], bfr[n], acc[m][n], 0, 0, 0);
        }
    }

    #pragma unroll
    for (int n = 0; n < 4; ++n) {
        int d = n0 + wc*64 + n*16 + r_l;
        float bb = ball[d];
        #pragma unroll
        for (int m = 0; m < 4; ++m) {
            int pr = m0 + wr*64 + m*16 + (kg_l << 2);
            #pragma unroll
            for (int r = 0; r < 4; ++r)
                VO[(size_t)(pr + r)*384 + d] = f2b(acc[m][n][r] + bb);
        }
    }
}

// ---------------- fused DCNv4 + GEMM2: out = SiLU(Wout @ dcn(VO)^T + bout) ----------------
// Round-13 structure (best known: 64-px blocks, grid 512, 64 KB LDS, 2 blocks/CU)
// + s_setprio(1) around the phase-2 MFMA cluster: with no inter-block sync, the
// CU's two blocks desync (one gathering, one in MFMA) -> priority lets the MFMA
// block issue ahead of the gather block's vmem storm (T5 regime).
__global__ __launch_bounds__(512, 4)
void dcn_gemm_kernel(const unsigned short* __restrict__ VO,
                     const unsigned short* __restrict__ Woutbf,
                     const float* __restrict__ bout, float* __restrict__ out)
{
    __shared__ unsigned short y_lds[16384];   // 32 KB: 4 sections x [64px][64k], swizzled
    __shared__ char u_buf[32768];             // 32 KB: phase1 om_s f32[64][108] | phase2 As
    float* om_s = reinterpret_cast<float*>(u_buf);
    unsigned short* As = reinterpret_cast<unsigned short*>(u_buf);

    int t = threadIdx.x;
    int bid = blockIdx.x;                     // 512 blocks = 8 XCD x 64
    int logical = ((bid & 7) << 6) + (bid >> 3);   // image == XCD
    int p0 = logical * 64;
    int nimg = p0 >> 12;
    int hw0 = p0 & 4095;
    int h = hw0 >> 6;                         // single image row; w == px

    const unsigned short* vimg = VO + (size_t)nimg * (HW * (size_t)DALL);

    // ---- stage om for 64 px into om_s (f32) ----
    for (int i = t; i < 6912; i += 512) {
        int pl = i / 108, j = i - pl * 108;
        om_s[pl * 108 + j] = b2f(vimg[(size_t)(hw0 + pl) * DALL + 256 + j]);
    }
    __syncthreads();

    // ---- phase 1: dcn, 4 slots per thread ----
    int ch8 = t & 7;
    #pragma unroll
    for (int iter = 0; iter < 4; ++iter) {
        int slotIdx = iter * 64 + (t >> 3);   // 0..255
        int px = slotIdx >> 2, g = slotIdx & 3;
        int w = px;
        const unsigned short* vbase = vimg + g*64 + ch8*8;
        const float* o = om_s + px*108 + g*27;

        f32x2 acc2[4] = {};
        #pragma unroll
        for (int k = 0; k < 9; ++k) {
            float dxo = o[2*k], dyo = o[2*k+1], m = o[18+k];
            float pxf = (float)(w + (k % 3) - 1) + dxo;
            float pyf = (float)(h + (k / 3) - 1) + dyo;
            float x0f = floorf(pxf), y0f = floorf(pyf);
            float fx = pxf - x0f, fy = pyf - y0f;
            int x0 = (int)x0f, y0 = (int)y0f;
            #pragma unroll
            for (int dyy = 0; dyy < 2; ++dyy) {
                #pragma unroll
                for (int dxx = 0; dxx < 2; ++dxx) {
                    int yy = y0 + dyy, xx = x0 + dxx;
                    bool valid = (yy >= 0) & (yy < HH) & (xx >= 0) & (xx < WW);
                    float wgt = (dyy ? fy : 1.f - fy) * (dxx ? fx : 1.f - fx);
                    float wmc = valid ? (m * wgt) : 0.f;
                    int yc = min(max(yy, 0), HH - 1);
                    int xc = min(max(xx, 0), WW - 1);
                    int4 v = *reinterpret_cast<const int4*>(
                        &vbase[((yc << 6) + xc) * DALL]);
                    f32x2 wm2; wm2[0] = wmc; wm2[1] = wmc;
                    int vv[4] = {v.x, v.y, v.z, v.w};
                    #pragma unroll
                    for (int q = 0; q < 4; ++q)
                        acc2[q] += bf2x(vv[q]) * wm2;
                }
            }
        }
        short8v ov;
        #pragma unroll
        for (int q = 0; q < 4; ++q) {
            ov[2*q]   = (short)f2b(acc2[q][0]);
            ov[2*q+1] = (short)f2b(acc2[q][1]);
        }
        // write into section g, row px, kg = ch8 (B-swizzled)
        *reinterpret_cast<short8v*>(
            &y_lds[g*4096 + px*64 + ((ch8 ^ (px & 7)) << 3)]) = ov;
    }

    // ---- phase 2: GEMM (M=256 d, N=64 px, K=256) ----
    int lane = t & 63;
    int wv = t >> 6;                          // 8 waves
    int wr = wv >> 1, wc = wv & 1;            // wr: 64-d band, wc: 32-px band
    int r_l = lane & 15, kg_l = lane >> 4;

    f32x4 acc[4][2] = {};
    for (int kt = 0; kt < 4; ++kt) {
        int c0 = kt * 64;
        __syncthreads();   // om_s/As free (phase1 done or prior kt MFMA done)
        #pragma unroll
        for (int i = 0; i < 4; ++i) {
            int idx = t + i * 512;            // 2048 jobs: row 0..255, kg 0..7
            int row = idx >> 3, kg = idx & 7;
            *reinterpret_cast<short8v*>(&As[row*64 + ((kg ^ (row & 7)) << 3)]) =
                *reinterpret_cast<const short8v*>(&Woutbf[(size_t)row*256 + c0 + kg*8]);
        }
        __syncthreads();
        __builtin_amdgcn_s_setprio(1);
        #pragma unroll
        for (int ks = 0; ks < 2; ++ks) {
            short8v af[4], bfr[2];
            #pragma unroll
            for (int m = 0; m < 4; ++m) {
                int row = wr*64 + m*16 + r_l;
                af[m] = *reinterpret_cast<const short8v*>(
                    &As[row*64 + (((ks*4 + kg_l) ^ (row & 7)) << 3)]);
            }
            #pragma unroll
            for (int n = 0; n < 2; ++n) {
                int row = wc*32 + n*16 + r_l;
                bfr[n] = *reinterpret_cast<const short8v*>(
                    &y_lds[kt*4096 + row*64 + (((ks*4 + kg_l) ^ (row & 7)) << 3)]);
            }
            #pragma unroll
            for (int m = 0; m < 4; ++m)
                #pragma unroll
                for (int n = 0; n < 2; ++n)
                    acc[m][n] = __builtin_amdgcn_mfma_f32_16x16x32_bf16(af[m], bfr[n], acc[m][n], 0, 0, 0);
        }
        __builtin_amdgcn_s_setprio(0);
    }

    // ---- epilogue: bias + SiLU + NCHW f32 store ----
    #pragma unroll
    for (int m = 0; m < 4; ++m) {
        int dbase = wr*64 + m*16 + (kg_l << 2);
        #pragma unroll
        for (int r = 0; r < 4; ++r) {
            int d = dbase + r;
            float bb = bout[d];
            #pragma unroll
            for (int n = 0; n < 2; ++n) {
                int pcol = wc*32 + n*16 + r_l;
                float z = acc[m][n][r] + bb;
                float sv = z / (1.f + __expf(-z));
                out[((size_t)(nimg*256 + d))*4096 + hw0 + pcol] = sv;
            }
        }
    }
}

extern "C" void kernel_launch(void* const* d_in, const int* in_sizes, int n_in,
                              void* d_out, int out_size, void* d_ws, size_t ws_size,
                              hipStream_t stream) {
    const float* x       = (const float*)d_in[0];
    const float* cv1_w   = (const float*)d_in[1];
    const float* cv1_b   = (const float*)d_in[2];
    const float* value_w = (const float*)d_in[3];
    const float* value_b = (const float*)d_in[4];
    const float* dw_w    = (const float*)d_in[5];
    const float* dw_b    = (const float*)d_in[6];
    const float* om_w    = (const float*)d_in[7];
    const float* om_b    = (const float*)d_in[8];
    const float* out_w   = (const float*)d_in[9];
    const float* cv2_w   = (const float*)d_in[10];
    const float* bn_g    = (const float*)d_in[11];
    const float* bn_b    = (const float*)d_in[12];
    const float* bn_m    = (const float*)d_in[13];
    const float* bn_v    = (const float*)d_in[14];

    char* ws = (char*)d_ws;
    unsigned short* VO     = (unsigned short*)(ws);
    unsigned short* Wallbf = (unsigned short*)(ws + 25165824);
    unsigned short* Woutbf = (unsigned short*)(ws + 25362432);
    float*          ball   = (float*)(ws + 25493504);
    float*          bout   = (float*)(ws + 25495040);
    float* out = (float*)d_out;

    prep_kernel<<<643, 256, 0, stream>>>(cv1_w, cv1_b, value_w, value_b, dw_w, dw_b,
                                         om_w, om_b, out_w, cv2_w,
                                         bn_g, bn_b, bn_m, bn_v,
                                         Wallbf, ball, Woutbf, bout);
    gemm_vo_kernel<<<dim3(3, 256), 256, 0, stream>>>(x, Wallbf, ball, VO);
    dcn_gemm_kernel<<<512, 512, 0, stream>>>(VO, Woutbf, bout, out);
}